// Round 5
// baseline (402.687 us; speedup 1.0000x reference)
//
#include <hip/hip_runtime.h>
#include <hip/hip_bf16.h>

#define N_ROWS 131072
#define DIM 64
#define K_CODES 1024
#define KSPLIT 4
#define KSEG (K_CODES / KSPLIT)   // 256 codes per wave
#define RPB 64                    // rows per block
#define CHUNK 16                  // codes per staged chunk (4 KB)
#define NCHUNK (KSEG / CHUNK)     // 16 chunks

typedef float v2f __attribute__((ext_vector_type(2)));
typedef const __attribute__((address_space(1))) void* gptr_t;
typedef __attribute__((address_space(3))) void* lptr_t;

// ws layout (floats): [0 .. K_CODES-1] = esq[k], [K_CODES] = loss accumulator

// esq[k] = np.sum(e*e, axis=1) with numpy's pairwise 8-accumulator order.
__global__ void vq_prep(const float* __restrict__ emb, float* __restrict__ ws) {
#pragma clang fp contract(off)
    int k = blockIdx.x * blockDim.x + threadIdx.x;
    if (k < K_CODES) {
        const float* e = emb + (size_t)k * DIM;
        float ee[DIM];
        #pragma unroll
        for (int d = 0; d < DIM; ++d) ee[d] = e[d] * e[d];
        float r[8];
        #pragma unroll
        for (int j = 0; j < 8; ++j) r[j] = ee[j];
        #pragma unroll
        for (int i = 8; i < DIM; i += 8)
            #pragma unroll
            for (int j = 0; j < 8; ++j) r[j] = r[j] + ee[i + j];
        ws[k] = ((r[0] + r[1]) + (r[2] + r[3])) + ((r[4] + r[5]) + (r[6] + r[7]));
    }
    if (blockIdx.x == 0 && threadIdx.x == 0) ws[K_CODES] = 0.f;
}

__global__ __launch_bounds__(256, 4) void vq_main(const float* __restrict__ x,
                                                  const float* __restrict__ emb,
                                                  const float* __restrict__ ws,
                                                  float* __restrict__ out,
                                                  float* __restrict__ loss_acc) {
#pragma clang fp contract(off)
    const int lane = threadIdx.x & 63;
    const int w = __builtin_amdgcn_readfirstlane((int)(threadIdx.x >> 6));
    const int row = blockIdx.x * RPB + lane;
    const int kbase = w * KSEG;

    // per-wave double-buffered embedding chunks: 4 waves x 2 bufs x 16 codes x 64 f
    __shared__ __align__(16) float elds[KSPLIT][2][CHUNK * DIM];
    __shared__ float sdist[KSPLIT][RPB];
    __shared__ int   sidx[KSPLIT][RPB];

    // stage chunk `c` of this wave's segment into buffer `buf`
    // (global src per-lane, LDS dst wave-uniform base + lane*16B)
    auto stage = [&](int c, int buf) {
        const float* gbase = emb + (size_t)(kbase + c * CHUNK) * DIM + lane * 4;
        #pragma unroll
        for (int i = 0; i < 4; ++i) {
            __builtin_amdgcn_global_load_lds((gptr_t)(gbase + i * 256),
                                             (lptr_t)&elds[w][buf][i * 256],
                                             16, 0, 0);
        }
    };

    stage(0, 0);  // prologue prefetch (latency hides under x-load + xsq)

    // x row in register PAIRS (pk ops need no pairing moves)
    v2f xv2[DIM / 2];
    const float4* xp = reinterpret_cast<const float4*>(x + (size_t)row * DIM);
    #pragma unroll
    for (int i = 0; i < DIM / 4; ++i) {
        float4 v = xp[i];
        xv2[2 * i + 0] = v2f{v.x, v.y};
        xv2[2 * i + 1] = v2f{v.z, v.w};
    }

    // xsq = np.sum(x*x): elementwise square then pairwise 8-accumulator (as R3/R4)
    float xsq;
    {
        float xx[DIM];
        #pragma unroll
        for (int i = 0; i < DIM / 2; ++i) {
            xx[2 * i + 0] = xv2[i].x * xv2[i].x;
            xx[2 * i + 1] = xv2[i].y * xv2[i].y;
        }
        float r[8];
        #pragma unroll
        for (int j = 0; j < 8; ++j) r[j] = xx[j];
        #pragma unroll
        for (int i = 8; i < DIM; i += 8)
            #pragma unroll
            for (int j = 0; j < 8; ++j) r[j] = r[j] + xx[i + j];
        xsq = ((r[0] + r[1]) + (r[2] + r[3])) + ((r[4] + r[5]) + (r[6] + r[7]));
    }

    float best = INFINITY;
    int bidx = 0;

    for (int c = 0; c < NCHUNK; ++c) {
        const int buf = c & 1;
        if (c + 1 < NCHUNK) {
            __builtin_amdgcn_sched_barrier(0);
            stage(c + 1, buf ^ 1);                     // prefetch next chunk
            asm volatile("s_waitcnt vmcnt(4)" ::: "memory");  // chunk c landed (in-order retire)
        } else {
            asm volatile("s_waitcnt vmcnt(0)" ::: "memory");
        }
        __builtin_amdgcn_sched_barrier(0);

        // consume 16 codes; numpy einsum emulation, bit-identical chain to R4:
        // 16-elem chunks, blocks in order 12,8,4,0; unfused mul then add;
        // lanes {0,1}->accA, {2,3}->accB; reduce (a0+a1)+(a2+a3).
        #pragma unroll 2
        for (int cc = 0; cc < CHUNK; ++cc) {
            const int k = kbase + c * CHUNK + cc;
            const float* ek = &elds[w][buf][cc * DIM];  // uniform addr -> broadcast ds_read
            v2f accA = v2f{0.f, 0.f};
            v2f accB = v2f{0.f, 0.f};
            #pragma unroll
            for (int c4 = 0; c4 < DIM; c4 += 16) {
                #pragma unroll
                for (int b = 12; b >= 0; b -= 4) {
                    const int d = c4 + b;
                    float4 ev = *reinterpret_cast<const float4*>(ek + d);
                    v2f ea = v2f{ev.x, ev.y};
                    v2f eb = v2f{ev.z, ev.w};
                    v2f pa, pb;
                    asm("v_pk_mul_f32 %0, %1, %2" : "=v"(pa) : "v"(ea), "v"(xv2[(d >> 1) + 0]));
                    asm("v_pk_mul_f32 %0, %1, %2" : "=v"(pb) : "v"(eb), "v"(xv2[(d >> 1) + 1]));
                    asm("v_pk_add_f32 %0, %1, %0" : "+v"(accA) : "v"(pa));
                    asm("v_pk_add_f32 %0, %1, %0" : "+v"(accB) : "v"(pb));
                }
            }
            float dot = (accA.x + accA.y) + (accB.x + accB.y);
            float t = xsq + ws[k];          // fl(xsq + esq), esq via s_load (4B/code)
            float dist = t - 2.0f * dot;    // fl(t - fl(2*dot)); 2*dot exact
            if (dist < best) { best = dist; bidx = k; }  // strict < == first-min
        }
    }

    // combine the 4 segments per row via LDS, in segment order (lowest k wins ties)
    sdist[w][lane] = best;
    sidx[w][lane]  = bidx;
    __syncthreads();

    if (w == 0) {
        float bestAll = sdist[0][lane];
        int   idxAll  = sidx[0][lane];
        #pragma unroll
        for (int s = 1; s < KSPLIT; ++s) {
            float ds_ = sdist[s][lane];
            int   is_ = sidx[s][lane];
            if (ds_ < bestAll) { bestAll = ds_; idxAll = is_; }
        }

        // epilogue (wave 0 owns all 64 rows; xv2 still in regs, static indexing)
        const float* q = emb + (size_t)idxAll * DIM;
        float* orow = out + (size_t)row * DIM;
        float lsum = 0.f;
        #pragma unroll
        for (int i = 0; i < DIM / 2; ++i) {
            const int d = 2 * i;
            float q0 = q[d + 0], q1 = q[d + 1];
            float df0 = q0 - xv2[i].x;
            float df1 = q1 - xv2[i].y;
            lsum = fmaf(df0, df0, lsum);
            lsum = fmaf(df1, df1, lsum);
            v2f o;
            o.x = xv2[i].x + df0;   // x + (q - x), reference op order
            o.y = xv2[i].y + df1;
            *reinterpret_cast<v2f*>(orow + d) = o;
        }

        out[(size_t)N_ROWS * DIM + row] = (float)idxAll;

        #pragma unroll
        for (int off = 32; off > 0; off >>= 1) lsum += __shfl_down(lsum, off, 64);
        if (lane == 0) atomicAdd(loss_acc, lsum);
    }
}

__global__ void vq_final(const float* __restrict__ loss_acc, float* __restrict__ out_loss) {
    if (threadIdx.x == 0 && blockIdx.x == 0) {
        float mean = loss_acc[0] / (float)((size_t)N_ROWS * DIM);
        out_loss[0] = mean;
    }
}

extern "C" void kernel_launch(void* const* d_in, const int* in_sizes, int n_in,
                              void* d_out, int out_size, void* d_ws, size_t ws_size,
                              hipStream_t stream) {
    const float* x   = (const float*)d_in[0];
    const float* emb = (const float*)d_in[1];
    float* out = (float*)d_out;
    float* ws = (float*)d_ws;

    vq_prep<<<dim3((K_CODES + 255) / 256), dim3(256), 0, stream>>>(emb, ws);
    vq_main<<<dim3(N_ROWS / RPB), dim3(256), 0, stream>>>(x, emb, ws, out, ws + K_CODES);
    vq_final<<<dim3(1), dim3(1), 0, stream>>>(ws + K_CODES,
                                              out + (size_t)N_ROWS * DIM + N_ROWS);
}